// Round 1
// baseline (4322.515 us; speedup 1.0000x reference)
//
#include <hip/hip_runtime.h>
#include <hip/hip_bf16.h>

typedef __bf16 bf16_t;
typedef __bf16 bf16x4 __attribute__((ext_vector_type(4)));
typedef __bf16 bf16x8 __attribute__((ext_vector_type(8)));
typedef float f32x4 __attribute__((ext_vector_type(4)));

constexpr int T_STEPS = 50;
constexpr int B_SZ = 1024;
constexpr int NP_SZ = 512;
constexpr int NH_SZ = 512;
constexpr int NG_SZ = 4096;

// ---------------- fp32 -> bf16 convert (x4 vectorized) ----------------
__global__ __launch_bounds__(256) void cvt_f32_bf16(const float* __restrict__ src,
                                                    bf16_t* __restrict__ dst, int n4) {
    int i = blockIdx.x * blockDim.x + threadIdx.x;
    if (i >= n4) return;
    float4 v = ((const float4*)src)[i];
    bf16x4 o;
    o[0] = (bf16_t)v.x; o[1] = (bf16_t)v.y; o[2] = (bf16_t)v.z; o[3] = (bf16_t)v.w;
    ((bf16x4*)dst)[i] = o;
}

// ---------------- generic bf16 MFMA GEMM: C = ep(A[M,K] @ B[N,K]^T) ----------------
// EP: 0 = +bias, f32 out | 1 = +bias, bf16 out | 2 = relu, bf16 out
//     3 = +vt@wih^T + bias + bias2, f32 out (LSTM gates)
template <int BM, int BN, int EP>
__global__ __launch_bounds__(256, 2) void gemm_bt(
    const bf16_t* __restrict__ A, const bf16_t* __restrict__ Bmat,
    const float* __restrict__ bias, const float* __restrict__ bias2,
    const float* __restrict__ vt, const float* __restrict__ wih,
    void* __restrict__ Cout, int M, int N, int K) {
    constexpr int BK = 32;
    constexpr int LDA = BK + 8;  // +8 bf16 pad: rows stride 80B -> 2-way bank alias (free)
    static_assert((BM * BK) % (256 * 8) == 0 && (BN * BK) % (256 * 8) == 0, "staging div");
    __shared__ bf16_t Als[BM * LDA];
    __shared__ bf16_t Bls[BN * LDA];

    const int tid = threadIdx.x;
    const int lane = tid & 63;
    const int wave = tid >> 6;
    const int wm = wave >> 1, wn = wave & 1;   // 2x2 wave grid
    const int quad = lane >> 4, l15 = lane & 15;

    const int bm0 = blockIdx.y * BM;
    const int bn0 = blockIdx.x * BN;

    constexpr int MT = BM / 32;  // 16-wide mfma tiles per wave (M)
    constexpr int NT = BN / 32;

    f32x4 acc[MT][NT];
#pragma unroll
    for (int i = 0; i < MT; i++)
#pragma unroll
        for (int j = 0; j < NT; j++) acc[i][j] = f32x4{0.f, 0.f, 0.f, 0.f};

    constexpr int LA = (BM * BK) / (256 * 8);
    constexpr int LB = (BN * BK) / (256 * 8);

    for (int k0 = 0; k0 < K; k0 += BK) {
#pragma unroll
        for (int i = 0; i < LA; i++) {
            int g = tid + i * 256;
            int r = g >> 2;            // BK/8 = 4 groups per row
            int c = (g & 3) << 3;
            *(bf16x8*)(&Als[r * LDA + c]) =
                *(const bf16x8*)(A + (size_t)(bm0 + r) * K + k0 + c);
        }
#pragma unroll
        for (int i = 0; i < LB; i++) {
            int g = tid + i * 256;
            int r = g >> 2;
            int c = (g & 3) << 3;
            *(bf16x8*)(&Bls[r * LDA + c]) =
                *(const bf16x8*)(Bmat + (size_t)(bn0 + r) * K + k0 + c);
        }
        __syncthreads();

        bf16x8 af[MT], bfg[NT];
#pragma unroll
        for (int i = 0; i < MT; i++)
            af[i] = *(const bf16x8*)(&Als[(wm * (BM / 2) + i * 16 + l15) * LDA + quad * 8]);
#pragma unroll
        for (int j = 0; j < NT; j++)
            bfg[j] = *(const bf16x8*)(&Bls[(wn * (BN / 2) + j * 16 + l15) * LDA + quad * 8]);

#pragma unroll
        for (int i = 0; i < MT; i++)
#pragma unroll
            for (int j = 0; j < NT; j++)
                acc[i][j] = __builtin_amdgcn_mfma_f32_16x16x32_bf16(af[i], bfg[j], acc[i][j], 0, 0, 0);
        __syncthreads();
    }

// epilogue: C/D layout col=lane&15, row=quad*4+reg  (verified gfx950 mapping)
#pragma unroll
    for (int i = 0; i < MT; i++) {
#pragma unroll
        for (int j = 0; j < NT; j++) {
            const int col = bn0 + wn * (BN / 2) + j * 16 + l15;
#pragma unroll
            for (int r = 0; r < 4; r++) {
                const int row = bm0 + wm * (BM / 2) + i * 16 + quad * 4 + r;
                float x = acc[i][j][r];
                if constexpr (EP == 0) {
                    x += bias[col];
                    ((float*)Cout)[(size_t)row * N + col] = x;
                } else if constexpr (EP == 1) {
                    x += bias[col];
                    ((bf16_t*)Cout)[(size_t)row * N + col] = (bf16_t)x;
                } else if constexpr (EP == 2) {
                    x = fmaxf(x, 0.f);
                    ((bf16_t*)Cout)[(size_t)row * N + col] = (bf16_t)x;
                } else {  // gates: + vt @ w_ih^T + b_ih + b_hh
                    x += vt[row * 2] * wih[col * 2] + vt[row * 2 + 1] * wih[col * 2 + 1] +
                         bias[col] + bias2[col];
                    ((float*)Cout)[(size_t)row * N + col] = x;
                }
            }
        }
    }
}

// ---------------- pointwise LSTM cell ----------------
__global__ __launch_bounds__(256) void lstm_cell(const float* __restrict__ gates,
                                                 float* __restrict__ cx,
                                                 bf16_t* __restrict__ hx) {
    int idx = blockIdx.x * blockDim.x + threadIdx.x;  // < B*NH
    int b = idx >> 9;                                  // / NH(512)
    int n = idx & 511;
    const float* gb = gates + ((size_t)b << 11);       // b * 4*NH
    float xi = gb[n];
    float xf = gb[512 + n];
    float xg = gb[1024 + n];
    float xo = gb[1536 + n];
    float ig = 1.f / (1.f + __expf(-xi));
    float fg = 1.f / (1.f + __expf(-xf));
    float gg = tanhf(xg);
    float og = 1.f / (1.f + __expf(-xo));
    float c = fg * cx[idx] + ig * gg;
    cx[idx] = c;
    hx[idx] = (bf16_t)(og * tanhf(c));
}

// ---------------- host launcher ----------------
extern "C" void kernel_launch(void* const* d_in, const int* in_sizes, int n_in,
                              void* d_out, int out_size, void* d_ws, size_t ws_size,
                              hipStream_t stream) {
    const float* v    = (const float*)d_in[0];
    const float* p0   = (const float*)d_in[1];
    const float* e1w  = (const float*)d_in[2];
    const float* e1b  = (const float*)d_in[3];
    const float* e2w  = (const float*)d_in[4];
    const float* e2b  = (const float*)d_in[5];
    const float* wih  = (const float*)d_in[6];
    const float* whh  = (const float*)d_in[7];
    const float* bih  = (const float*)d_in[8];
    const float* bhh  = (const float*)d_in[9];
    const float* gw   = (const float*)d_in[10];
    const float* decw = (const float*)d_in[11];
    const float* decb = (const float*)d_in[12];
    float* out = (float*)d_out;

    size_t off = 0;
    auto take = [&](size_t bytes) {
        size_t o = off;
        off += (bytes + 255) & ~(size_t)255;
        return (void*)((char*)d_ws + o);
    };
    bf16_t* p0b   = (bf16_t*)take((size_t)B_SZ * NP_SZ * 2);
    bf16_t* e1wb  = (bf16_t*)take((size_t)NH_SZ * NP_SZ * 2);
    bf16_t* e2wb  = (bf16_t*)take((size_t)NH_SZ * NP_SZ * 2);
    bf16_t* whhb  = (bf16_t*)take((size_t)4 * NH_SZ * NH_SZ * 2);
    bf16_t* gwb   = (bf16_t*)take((size_t)NG_SZ * NH_SZ * 2);
    bf16_t* decwb = (bf16_t*)take((size_t)NP_SZ * NG_SZ * 2);
    bf16_t* hxb   = (bf16_t*)take((size_t)B_SZ * NH_SZ * 2);
    float*  cxf   = (float*)take((size_t)B_SZ * NH_SZ * 4);
    float*  gatesf = (float*)take((size_t)B_SZ * 4 * NH_SZ * 4);

    // decoder path selection (fixed per harness since ws_size is constant -> graph-safe)
    const size_t need_big = (size_t)T_STEPS * B_SZ * NG_SZ * 2;  // g_seq bf16, ~400MB
    const size_t need_small = (size_t)B_SZ * NG_SZ * 2;
    bool big = (ws_size > off) && (ws_size - off >= need_big);
    bf16_t* gbuf = (bf16_t*)take(big ? need_big : need_small);

    auto cvt = [&](const float* s, bf16_t* d, int n) {
        int n4 = n >> 2;
        cvt_f32_bf16<<<dim3((n4 + 255) / 256), dim3(256), 0, stream>>>(s, d, n4);
    };
    cvt(p0, p0b, B_SZ * NP_SZ);
    cvt(e1w, e1wb, NH_SZ * NP_SZ);
    cvt(e2w, e2wb, NH_SZ * NP_SZ);
    cvt(whh, whhb, 4 * NH_SZ * NH_SZ);
    cvt(gw, gwb, NG_SZ * NH_SZ);
    cvt(decw, decwb, NP_SZ * NG_SZ);

    // encoder: hx0 (bf16 out), cx0 (f32 out)
    gemm_bt<64, 64, 1><<<dim3(NH_SZ / 64, B_SZ / 64), 256, 0, stream>>>(
        p0b, e1wb, e1b, nullptr, nullptr, nullptr, hxb, B_SZ, NH_SZ, NP_SZ);
    gemm_bt<64, 64, 0><<<dim3(NH_SZ / 64, B_SZ / 64), 256, 0, stream>>>(
        p0b, e2wb, e2b, nullptr, nullptr, nullptr, cxf, B_SZ, NH_SZ, NP_SZ);

    for (int t = 0; t < T_STEPS; t++) {
        const float* vt = v + (size_t)t * B_SZ * 2;
        // gates = hx@w_hh^T + vt@w_ih^T + b_ih + b_hh   [B, 4*NH], 256 blocks
        gemm_bt<64, 128, 3><<<dim3(4 * NH_SZ / 128, B_SZ / 64), 256, 0, stream>>>(
            hxb, whhb, bih, bhh, vt, wih, gatesf, B_SZ, 4 * NH_SZ, NH_SZ);
        // cell pointwise
        lstm_cell<<<dim3(B_SZ * NH_SZ / 256), 256, 0, stream>>>(gatesf, cxf, hxb);
        // g = relu(hx @ g_w^T)  [B, NG], 256 blocks
        bf16_t* gt = big ? gbuf + (size_t)t * B_SZ * NG_SZ : gbuf;
        gemm_bt<128, 128, 2><<<dim3(NG_SZ / 128, B_SZ / 128), 256, 0, stream>>>(
            hxb, gwb, nullptr, nullptr, nullptr, nullptr, gt, B_SZ, NG_SZ, NH_SZ);
        if (!big) {
            // per-step decoder fallback: preds_t = g @ dec_w^T + dec_b  [B, NP]
            gemm_bt<64, 64, 0><<<dim3(NP_SZ / 64, B_SZ / 64), 256, 0, stream>>>(
                gbuf, decwb, decb, nullptr, nullptr, nullptr,
                out + (size_t)t * B_SZ * NP_SZ, B_SZ, NP_SZ, NG_SZ);
        }
    }
    if (big) {
        // batched decoder over all T: [T*B, NG] @ [NG, NP]^T
        gemm_bt<128, 128, 0><<<dim3(NP_SZ / 128, (T_STEPS * B_SZ) / 128), 256, 0, stream>>>(
            gbuf, decwb, decb, nullptr, nullptr, nullptr, out, T_STEPS * B_SZ, NP_SZ, NG_SZ);
    }
}

// Round 2
// 2416.400 us; speedup vs baseline: 1.7888x; 1.7888x over previous
//
#include <hip/hip_runtime.h>
#include <hip/hip_bf16.h>

typedef __bf16 bf16_t;
typedef __bf16 bf16x4 __attribute__((ext_vector_type(4)));
typedef __bf16 bf16x8 __attribute__((ext_vector_type(8)));
typedef float f32x4 __attribute__((ext_vector_type(4)));

constexpr int T_STEPS = 50;
constexpr int B_SZ = 1024;
constexpr int NP_SZ = 512;
constexpr int NH_SZ = 512;
constexpr int NG_SZ = 4096;

// async 16B/lane global->LDS. LDS dest is wave-uniform base; HW deposits lane i at base + i*16.
__device__ __forceinline__ void async16(const bf16_t* g, bf16_t* l) {
    __builtin_amdgcn_global_load_lds((const __attribute__((address_space(1))) void*)g,
                                     (__attribute__((address_space(3))) void*)l, 16, 0, 0);
}

// ---------------- fp32 -> bf16 convert ----------------
__global__ __launch_bounds__(256) void cvt_f32_bf16(const float* __restrict__ src,
                                                    bf16_t* __restrict__ dst, int n4) {
    int i = blockIdx.x * blockDim.x + threadIdx.x;
    if (i >= n4) return;
    float4 v = ((const float4*)src)[i];
    bf16x4 o;
    o[0] = (bf16_t)v.x; o[1] = (bf16_t)v.y; o[2] = (bf16_t)v.z; o[3] = (bf16_t)v.w;
    ((bf16x4*)dst)[i] = o;
}

// ---------------- m97-style GEMM: C = ep(A[M,K] @ B[N,K]^T) ----------------
// LDS layout: fragment order. Sub-tile s (16 rows x 32 cols) = 64 lanes x 16B contiguous.
// Lane l holds rows (s*16 + (l&15)), cols k0 + (l>>4)*8 .. +8  == exactly its MFMA fragment.
// EP: 0 = +bias f32 out | 1 = +bias bf16 out | 2 = relu bf16 out
template <int BM, int BN, int EP>
__global__ __launch_bounds__(256) void gemm16(const bf16_t* __restrict__ A,
                                              const bf16_t* __restrict__ Bm,
                                              const float* __restrict__ bias,
                                              void* __restrict__ Cout, int M, int N, int K) {
    constexpr int ASUB = BM / 16, BSUB = BN / 16, NSUB = ASUB + BSUB;
    static_assert(NSUB % 4 == 0, "subtile split");
    constexpr int PER_WAVE = NSUB / 4;
    constexpr int MT = BM / 32, NT = BN / 32;
    __shared__ bf16_t lds[NSUB * 512];

    const int tid = threadIdx.x, lane = tid & 63, wave = tid >> 6;
    const int wm = wave >> 1, wn = wave & 1;
    const int l15 = lane & 15, quad = lane >> 4;
    const int bm0 = blockIdx.y * BM, bn0 = blockIdx.x * BN;

    // per-lane staging source pointers (advance by 32 elems per K-iter)
    const bf16_t* gsrc[PER_WAVE];
    bf16_t* ldst[PER_WAVE];
#pragma unroll
    for (int q = 0; q < PER_WAVE; q++) {
        int s = wave * PER_WAVE + q;
        if (s < ASUB)
            gsrc[q] = A + (size_t)(bm0 + s * 16 + l15) * K + quad * 8;
        else
            gsrc[q] = Bm + (size_t)(bn0 + (s - ASUB) * 16 + l15) * K + quad * 8;
        ldst[q] = &lds[s * 512];
    }

    f32x4 acc[MT][NT];
#pragma unroll
    for (int i = 0; i < MT; i++)
#pragma unroll
        for (int j = 0; j < NT; j++) acc[i][j] = f32x4{0.f, 0.f, 0.f, 0.f};

    for (int k0 = 0; k0 < K; k0 += 32) {
        __syncthreads();  // previous iter's ds_reads complete before overwrite
#pragma unroll
        for (int q = 0; q < PER_WAVE; q++) async16(gsrc[q] + k0, ldst[q]);
        __syncthreads();  // staging complete (vmcnt drain + barrier)

        bf16x8 af[MT], bfg[NT];
#pragma unroll
        for (int i = 0; i < MT; i++)
            af[i] = *(const bf16x8*)&lds[(wm * MT + i) * 512 + lane * 8];
#pragma unroll
        for (int j = 0; j < NT; j++)
            bfg[j] = *(const bf16x8*)&lds[(ASUB + wn * NT + j) * 512 + lane * 8];
#pragma unroll
        for (int i = 0; i < MT; i++)
#pragma unroll
            for (int j = 0; j < NT; j++)
                acc[i][j] = __builtin_amdgcn_mfma_f32_16x16x32_bf16(af[i], bfg[j], acc[i][j], 0, 0, 0);
    }

// epilogue: C/D layout col=lane&15, row=quad*4+reg
#pragma unroll
    for (int j = 0; j < NT; j++) {
        const int col = bn0 + wn * (BN / 2) + j * 16 + l15;
        float bb = (EP == 2) ? 0.f : bias[col];
#pragma unroll
        for (int i = 0; i < MT; i++) {
#pragma unroll
            for (int r = 0; r < 4; r++) {
                const int row = bm0 + wm * (BM / 2) + i * 16 + quad * 4 + r;
                float x = acc[i][j][r];
                if constexpr (EP == 0) {
                    ((float*)Cout)[(size_t)row * N + col] = x + bb;
                } else if constexpr (EP == 1) {
                    ((bf16_t*)Cout)[(size_t)row * N + col] = (bf16_t)(x + bb);
                } else {
                    ((bf16_t*)Cout)[(size_t)row * N + col] = (bf16_t)fmaxf(x, 0.f);
                }
            }
        }
    }
}

// ---------------- fused gates GEMM + LSTM cell ----------------
// Block computes a 64(row b) x 32(col n) tile of hx/cx; accumulates all 4 gate slices
// of w_hh for those n. Epilogue: gates -> cell -> cx(f32), hx(bf16).
__global__ __launch_bounds__(256) void gates_cell(
    const bf16_t* __restrict__ hx_in, const bf16_t* __restrict__ whh,
    const float* __restrict__ vt, const float* __restrict__ wih,
    const float* __restrict__ bih, const float* __restrict__ bhh,
    float* __restrict__ cx, bf16_t* __restrict__ hx_out) {
    // sub-tiles: 0..3 = A (64 rows of hx), 4..11 = B (4 gates x 2 halves of 32 n-cols)
    __shared__ bf16_t lds[12 * 512];
    const int tid = threadIdx.x, lane = tid & 63, wave = tid >> 6;
    const int wm = wave >> 1, wn = wave & 1;
    const int l15 = lane & 15, quad = lane >> 4;
    const int bm0 = blockIdx.y * 64, bn0 = blockIdx.x * 32;

    const bf16_t* gsrc[3];
    bf16_t* ldst[3];
#pragma unroll
    for (int q = 0; q < 3; q++) {
        int s = wave * 3 + q;
        if (s < 4) {
            gsrc[q] = hx_in + (size_t)(bm0 + s * 16 + l15) * NH_SZ + quad * 8;
        } else {
            int sb = s - 4, gi = sb >> 1, h = sb & 1;
            gsrc[q] = whh + (size_t)(gi * NH_SZ + bn0 + h * 16 + l15) * NH_SZ + quad * 8;
        }
        ldst[q] = &lds[s * 512];
    }

    f32x4 acc[4][2];
#pragma unroll
    for (int g = 0; g < 4; g++)
#pragma unroll
        for (int i = 0; i < 2; i++) acc[g][i] = f32x4{0.f, 0.f, 0.f, 0.f};

    for (int k0 = 0; k0 < NH_SZ; k0 += 32) {
        __syncthreads();
#pragma unroll
        for (int q = 0; q < 3; q++) async16(gsrc[q] + k0, ldst[q]);
        __syncthreads();

        bf16x8 af[2], bg[4];
#pragma unroll
        for (int i = 0; i < 2; i++)
            af[i] = *(const bf16x8*)&lds[(wm * 2 + i) * 512 + lane * 8];
#pragma unroll
        for (int g = 0; g < 4; g++)
            bg[g] = *(const bf16x8*)&lds[(4 + g * 2 + wn) * 512 + lane * 8];
#pragma unroll
        for (int g = 0; g < 4; g++)
#pragma unroll
            for (int i = 0; i < 2; i++)
                acc[g][i] = __builtin_amdgcn_mfma_f32_16x16x32_bf16(af[i], bg[g], acc[g][i], 0, 0, 0);
    }

    const int col = bn0 + wn * 16 + l15;
    float bi[4], w0[4], w1[4];
#pragma unroll
    for (int g = 0; g < 4; g++) {
        int gc = g * NH_SZ + col;
        bi[g] = bih[gc] + bhh[gc];
        w0[g] = wih[gc * 2];
        w1[g] = wih[gc * 2 + 1];
    }
#pragma unroll
    for (int i = 0; i < 2; i++) {
#pragma unroll
        for (int r = 0; r < 4; r++) {
            const int row = bm0 + wm * 32 + i * 16 + quad * 4 + r;
            float v0 = vt[row * 2], v1 = vt[row * 2 + 1];
            float xi = acc[0][i][r] + bi[0] + v0 * w0[0] + v1 * w1[0];
            float xf = acc[1][i][r] + bi[1] + v0 * w0[1] + v1 * w1[1];
            float xg = acc[2][i][r] + bi[2] + v0 * w0[2] + v1 * w1[2];
            float xo = acc[3][i][r] + bi[3] + v0 * w0[3] + v1 * w1[3];
            float ig = 1.f / (1.f + __expf(-xi));
            float fg = 1.f / (1.f + __expf(-xf));
            float gg = tanhf(xg);
            float og = 1.f / (1.f + __expf(-xo));
            int idx = (row << 9) + col;
            float c = fg * cx[idx] + ig * gg;
            cx[idx] = c;
            hx_out[idx] = (bf16_t)(og * tanhf(c));
        }
    }
}

// ---------------- host launcher ----------------
extern "C" void kernel_launch(void* const* d_in, const int* in_sizes, int n_in,
                              void* d_out, int out_size, void* d_ws, size_t ws_size,
                              hipStream_t stream) {
    const float* v    = (const float*)d_in[0];
    const float* p0   = (const float*)d_in[1];
    const float* e1w  = (const float*)d_in[2];
    const float* e1b  = (const float*)d_in[3];
    const float* e2w  = (const float*)d_in[4];
    const float* e2b  = (const float*)d_in[5];
    const float* wih  = (const float*)d_in[6];
    const float* whh  = (const float*)d_in[7];
    const float* bih  = (const float*)d_in[8];
    const float* bhh  = (const float*)d_in[9];
    const float* gw   = (const float*)d_in[10];
    const float* decw = (const float*)d_in[11];
    const float* decb = (const float*)d_in[12];
    float* out = (float*)d_out;

    size_t off = 0;
    auto take = [&](size_t bytes) {
        size_t o = off;
        off += (bytes + 255) & ~(size_t)255;
        return (void*)((char*)d_ws + o);
    };
    bf16_t* p0b   = (bf16_t*)take((size_t)B_SZ * NP_SZ * 2);
    bf16_t* e1wb  = (bf16_t*)take((size_t)NH_SZ * NP_SZ * 2);
    bf16_t* e2wb  = (bf16_t*)take((size_t)NH_SZ * NP_SZ * 2);
    bf16_t* whhb  = (bf16_t*)take((size_t)4 * NH_SZ * NH_SZ * 2);
    bf16_t* gwb   = (bf16_t*)take((size_t)NG_SZ * NH_SZ * 2);
    bf16_t* decwb = (bf16_t*)take((size_t)NP_SZ * NG_SZ * 2);
    bf16_t* hxA   = (bf16_t*)take((size_t)B_SZ * NH_SZ * 2);
    bf16_t* hxB   = (bf16_t*)take((size_t)B_SZ * NH_SZ * 2);
    float*  cxf   = (float*)take((size_t)B_SZ * NH_SZ * 4);

    // decoder chunk size: largest divisor of T that fits remaining workspace
    const size_t per_step = (size_t)B_SZ * NG_SZ * 2;  // 8 MB bf16
    int C = 1;
    for (int c : {25, 10, 5, 2, 1}) {
        if (off + (size_t)c * per_step <= ws_size) { C = c; break; }
    }
    bf16_t* gbuf = (bf16_t*)take((size_t)C * per_step);

    auto cvt = [&](const float* s, bf16_t* d, int n) {
        int n4 = n >> 2;
        cvt_f32_bf16<<<dim3((n4 + 255) / 256), dim3(256), 0, stream>>>(s, d, n4);
    };
    cvt(p0, p0b, B_SZ * NP_SZ);
    cvt(e1w, e1wb, NH_SZ * NP_SZ);
    cvt(e2w, e2wb, NH_SZ * NP_SZ);
    cvt(whh, whhb, 4 * NH_SZ * NH_SZ);
    cvt(gw, gwb, NG_SZ * NH_SZ);
    cvt(decw, decwb, NP_SZ * NG_SZ);

    // encoders: hx0 (bf16), cx0 (f32). 64x64 tiles -> 128 blocks each.
    gemm16<64, 64, 1><<<dim3(NH_SZ / 64, B_SZ / 64), 256, 0, stream>>>(
        p0b, e1wb, e1b, hxA, B_SZ, NH_SZ, NP_SZ);
    gemm16<64, 64, 0><<<dim3(NH_SZ / 64, B_SZ / 64), 256, 0, stream>>>(
        p0b, e2wb, e2b, cxf, B_SZ, NH_SZ, NP_SZ);

    bf16_t* hin = hxA;
    bf16_t* hout = hxB;
    for (int t = 0; t < T_STEPS; t++) {
        const float* vt = v + (size_t)t * B_SZ * 2;
        // fused gates + cell: grid (NH/32, B/64) = (16,16) = 256 blocks
        gates_cell<<<dim3(NH_SZ / 32, B_SZ / 64), 256, 0, stream>>>(
            hin, whhb, vt, wih, bih, bhh, cxf, hout);
        // g = relu(hx @ g_w^T): 128x128 tiles -> (32,8) = 256 blocks
        gemm16<128, 128, 2><<<dim3(NG_SZ / 128, B_SZ / 128), 256, 0, stream>>>(
            hout, gwb, nullptr, gbuf + (size_t)(t % C) * B_SZ * NG_SZ, B_SZ, NG_SZ, NH_SZ);
        // chunked batched decoder
        if ((t + 1) % C == 0) {
            int t0 = t + 1 - C;
            gemm16<128, 128, 0><<<dim3(NP_SZ / 128, (C * B_SZ) / 128), 256, 0, stream>>>(
                gbuf, decwb, decb, out + (size_t)t0 * B_SZ * NP_SZ, C * B_SZ, NP_SZ, NG_SZ);
        }
        // swap hx buffers
        bf16_t* tmp = hin; hin = hout; hout = tmp;
    }
}